// Round 9
// baseline (530.953 us; speedup 1.0000x reference)
//
#include <hip/hip_runtime.h>
#include <hip/hip_bf16.h>

#define NNODES 100000
#define NEDGES 1600000
#define VOCAB 50000
#define HDIM 256
#define ADIM 64
#define NHEADS 3
#define FDIM 192   // NHEADS*ADIM
#define NGRAPH 64
#define NPART 64

#define CONV_ELEMS (HDIM * FDIM + 128 * 64 + 16 * 128)   // 59392
#define CONV_BLOCKS ((CONV_ELEMS + 255) / 256)            // 232
#define HIST_BLOCKS ((NEDGES + 255) / 256)                // 6250
#define PROJ_BLOCKS ((VOCAB + 63) / 64)                   // 782

typedef __attribute__((ext_vector_type(8))) short bf16x8;  // 8 bf16 = 4 VGPRs
typedef __attribute__((ext_vector_type(4))) float f32x4;

__device__ __forceinline__ float bf2f(unsigned short u) {
  return __uint_as_float((unsigned int)u << 16);
}
__device__ __forceinline__ unsigned short f2bf(float f) {
  unsigned int u = __float_as_uint(f);
  u += 0x7FFFu + ((u >> 16) & 1u);   // round-nearest-even
  return (unsigned short)(u >> 16);
}

// ---- fused: weight transpose/cast (blocks 0..231)  ||  hist+rank (rest) ----
__global__ __launch_bounds__(256) void conv_hist_kernel(
    const float* __restrict__ Wfc, const float* __restrict__ W1,
    const float* __restrict__ W2, unsigned short* __restrict__ Wt,
    unsigned short* __restrict__ W1t, unsigned short* __restrict__ W2t,
    const int* __restrict__ dst, int* __restrict__ cnt,
    unsigned short* __restrict__ rank16)
{
  if (blockIdx.x < CONV_BLOCKS) {
    int i = blockIdx.x * 256 + threadIdx.x;
    if (i < HDIM * FDIM) {
      int c = i / HDIM, k = i % HDIM;
      Wt[i] = f2bf(Wfc[(size_t)k * FDIM + c]);
    } else if (i < HDIM * FDIM + 128 * 64) {
      int j = i - HDIM * FDIM;
      int c = j / 64, k = j % 64;
      W1t[j] = f2bf(W1[(size_t)k * 128 + c]);
    } else if (i < CONV_ELEMS) {
      int j = i - HDIM * FDIM - 128 * 64;
      int c = j / 128, k = j % 128;
      W2t[j] = f2bf(W2[(size_t)k * 16 + c]);
    }
  } else {
    int e = (blockIdx.x - CONV_BLOCKS) * 256 + threadIdx.x;
    if (e < NEDGES) rank16[e] = (unsigned short)atomicAdd(&cnt[dst[e]], 1);
  }
}

// ---- single-block exclusive scan of cnt[0..N) -> offs[0..N] ---------------
__global__ __launch_bounds__(1024) void scan_fused_kernel(
    const int* __restrict__ cnt, int* __restrict__ offs, int n)
{
  __shared__ int sd[1024];
  const int C = 98;                  // 98*1024 >= 100000
  int t = threadIdx.x;
  int start = t * C, end = start + C;
  if (start > n) start = n;
  if (end > n) end = n;
  int s = 0;
  for (int i = start; i < end; ++i) s += cnt[i];
  sd[t] = s;
  __syncthreads();
  for (int o = 1; o < 1024; o <<= 1) {
    int v = (t >= o) ? sd[t - o] : 0;
    __syncthreads();
    sd[t] += v;
    __syncthreads();
  }
  int run = sd[t] - s;               // exclusive prefix of this chunk
  for (int i = start; i < end; ++i) {
    offs[i] = run;
    run += cnt[i];
  }
  if (t == 1023) offs[n] = run;      // == total
}

// ---- fused: proj GEMM + attn dots (blocks 0..781)  ||  scatter (rest) ------
__global__ __launch_bounds__(256) void proj_scatter_kernel(
    const float* __restrict__ emb,              // [V][256] f32
    const unsigned short* __restrict__ Wt,      // [192][256] bf16
    const float* __restrict__ attn_l, const float* __restrict__ attn_r,
    unsigned short* __restrict__ proj_bf,       // [V][192]
    float4* __restrict__ elv4, float4* __restrict__ erv4,
    const int* __restrict__ src, const int* __restrict__ dst,
    const int* __restrict__ h0, const unsigned short* __restrict__ rank16,
    const int* __restrict__ offs, unsigned short* __restrict__ recs16)
{
  if (blockIdx.x >= PROJ_BLOCKS) {
    int e = (blockIdx.x - PROJ_BLOCKS) * 256 + threadIdx.x;
    if (e < NEDGES) {
      int p = offs[dst[e]] + (int)rank16[e];
      recs16[p] = (unsigned short)h0[src[e]];
    }
    return;
  }
  const int wave = threadIdx.x >> 6;
  const int lane = threadIdx.x & 63;
  const int row0 = blockIdx.x * 64 + wave * 16;
  const int cb = lane & 15;
  const int q  = lane >> 4;
  int arow = row0 + cb;
  if (arow >= VOCAB) arow = VOCAB - 1;          // clamp loads; stores guarded
  const int kgrp = q * 8;

  f32x4 acc[12];
#pragma unroll
  for (int c = 0; c < 12; ++c) acc[c] = (f32x4){0.f, 0.f, 0.f, 0.f};

  const float* arow_p = &emb[(size_t)arow * HDIM + kgrp];
  const unsigned short* bcol_p = &Wt[(size_t)cb * HDIM + kgrp];

#pragma unroll
  for (int ks = 0; ks < 8; ++ks) {
    float4 f0 = *reinterpret_cast<const float4*>(arow_p + ks * 32);
    float4 f1 = *reinterpret_cast<const float4*>(arow_p + ks * 32 + 4);
    bf16x8 a;
    a[0] = (short)f2bf(f0.x); a[1] = (short)f2bf(f0.y);
    a[2] = (short)f2bf(f0.z); a[3] = (short)f2bf(f0.w);
    a[4] = (short)f2bf(f1.x); a[5] = (short)f2bf(f1.y);
    a[6] = (short)f2bf(f1.z); a[7] = (short)f2bf(f1.w);
#pragma unroll
    for (int c = 0; c < 12; ++c) {
      bf16x8 b = *reinterpret_cast<const bf16x8*>(bcol_p + (size_t)c * 16 * HDIM + ks * 32);
      acc[c] = __builtin_amdgcn_mfma_f32_16x16x32_bf16(a, b, acc[c], 0, 0, 0);
    }
  }

  const int rb = row0 + 4 * q;
#pragma unroll
  for (int i = 0; i < 4; ++i) {
    int r = rb + i;
    if (r < VOCAB) {
#pragma unroll
      for (int c = 0; c < 12; ++c)
        proj_bf[(size_t)r * FDIM + c * 16 + cb] = f2bf(acc[c][i]);
    }
  }

  // fused attention dots
  float al_v[12], ar_v[12];
#pragma unroll
  for (int c = 0; c < 12; ++c) {
    al_v[c] = attn_l[c * 16 + cb];
    ar_v[c] = attn_r[c * 16 + cb];
  }
  float elp[4][3], erp[4][3];
#pragma unroll
  for (int i = 0; i < 4; ++i)
#pragma unroll
    for (int h = 0; h < 3; ++h) {
      float sl = 0.f, sr = 0.f;
#pragma unroll
      for (int cc = 0; cc < 4; ++cc) {
        float v = acc[h * 4 + cc][i];
        sl += v * al_v[h * 4 + cc];
        sr += v * ar_v[h * 4 + cc];
      }
      elp[i][h] = sl; erp[i][h] = sr;
    }
#pragma unroll
  for (int s = 8; s > 0; s >>= 1) {
#pragma unroll
    for (int i = 0; i < 4; ++i)
#pragma unroll
      for (int h = 0; h < 3; ++h) {
        elp[i][h] += __shfl_xor(elp[i][h], s, 64);
        erp[i][h] += __shfl_xor(erp[i][h], s, 64);
      }
  }
  if (cb == 0) {
#pragma unroll
    for (int i = 0; i < 4; ++i) {
      int r = rb + i;
      if (r < VOCAB) {
        elv4[r] = make_float4(elp[i][0], elp[i][1], elp[i][2], 0.f);
        erv4[r] = make_float4(erp[i][0], erp[i][1], erp[i][2], 0.f);
      }
    }
  }
}

// ---- per-node weights, WAVE-parallel: lanes own edges; coalesced wrec ------
__global__ __launch_bounds__(256) void wexp_kernel(
    const unsigned short* __restrict__ recs16, const int* __restrict__ offs,
    const int* __restrict__ h0,
    const float4* __restrict__ elv4, const float4* __restrict__ erv4,
    uint2* __restrict__ wrec, float4* __restrict__ inv4, int N)
{
  int lane = threadIdx.x & 63;
  int n = blockIdx.x * 4 + (threadIdx.x >> 6);
  if (n >= N) return;
  const float4 ero = erv4[h0[n]];
  int lo = offs[n], hi = offs[n + 1];
  float d0 = 0.f, d1 = 0.f, d2 = 0.f;
  for (int c = lo + lane; c < hi; c += 64) {
    unsigned v = recs16[c];
    float4 ev = elv4[v];
    float e0 = ev.x + ero.x, e1 = ev.y + ero.y, e2 = ev.z + ero.z;
    e0 = e0 > 0.f ? e0 : 0.2f * e0;   // leaky_relu 0.2
    e1 = e1 > 0.f ? e1 : 0.2f * e1;
    e2 = e2 > 0.f ? e2 : 0.2f * e2;
    unsigned short u0 = f2bf(__expf(e0));
    unsigned short u1 = f2bf(__expf(e1));
    unsigned short u2 = f2bf(__expf(e2));
    d0 += bf2f(u0); d1 += bf2f(u1); d2 += bf2f(u2);   // sum ROUNDED w
    wrec[c] = make_uint2(v | ((unsigned)u0 << 16),
                         (unsigned)u1 | ((unsigned)u2 << 16));
  }
#pragma unroll
  for (int s = 32; s > 0; s >>= 1) {
    d0 += __shfl_xor(d0, s, 64);
    d1 += __shfl_xor(d1, s, 64);
    d2 += __shfl_xor(d2, s, 64);
  }
  if (lane == 0)
    inv4[n] = make_float4(d0 > 0.f ? 1.f / d0 : 0.f,
                          d1 > 0.f ? 1.f / d1 : 0.f,
                          d2 > 0.f ? 1.f / d2 : 0.f, 0.f);
}

// ---- fused aggregation (64 nodes/block, wave=16 nodes) + MFMA MLP ----------
__global__ __launch_bounds__(256) void aggmlp_kernel(
    const uint2* __restrict__ wrec, const int* __restrict__ offs,
    const float4* __restrict__ inv4,
    const unsigned short* __restrict__ proj_bf, const float* __restrict__ bias_gat,
    const unsigned short* __restrict__ W1t,    // [128][64]
    const float* __restrict__ b1,
    const unsigned short* __restrict__ W2t,    // [16][128]
    const float* __restrict__ b2, const int* __restrict__ gid,
    float* __restrict__ sums_priv, float* __restrict__ counts_priv, int N)
{
  __shared__ unsigned short h2s[64 * 64];      // XOR-swizzled (row&7)<<4 bytes
  __shared__ unsigned short z_lds[64 * 128];
  char* h2b = (char*)h2s;
  const int wave = threadIdx.x >> 6;
  const int lane = threadIdx.x & 63;
  const int base = blockIdx.x * 64;

  // ---- aggregation: wave handles 16 nodes serially, lane = feature slot ----
  float bg0 = bias_gat[lane], bg1 = bias_gat[64 + lane], bg2 = bias_gat[128 + lane];
  for (int i = 0; i < 16; ++i) {
    int ln = wave * 16 + i;
    int n = base + ln;
    float h2 = 0.f;
    if (n < N) {
      int lo = offs[n], hi = offs[n + 1];
      float a0 = 0.f, a1 = 0.f, a2 = 0.f;
      int idx = lo;
      for (; idx + 8 <= hi; idx += 8) {
        uint2 r[8];
#pragma unroll
        for (int t = 0; t < 8; ++t) r[t] = wrec[idx + t];
        const unsigned short* ps[8];
#pragma unroll
        for (int t = 0; t < 8; ++t)
          ps[t] = &proj_bf[(size_t)(r[t].x & 0xFFFFu) * FDIM];
        float g0[8], g1[8], g2[8];
#pragma unroll
        for (int t = 0; t < 8; ++t) {   // 24 independent gathers in flight
          g0[t] = bf2f(ps[t][lane]);
          g1[t] = bf2f(ps[t][64 + lane]);
          g2[t] = bf2f(ps[t][128 + lane]);
        }
#pragma unroll
        for (int t = 0; t < 8; ++t) {
          a0 += bf2f((unsigned short)(r[t].x >> 16)) * g0[t];
          a1 += bf2f((unsigned short)(r[t].y & 0xFFFFu)) * g1[t];
          a2 += bf2f((unsigned short)(r[t].y >> 16)) * g2[t];
        }
      }
      for (; idx < hi; ++idx) {
        uint2 r = wrec[idx];
        const unsigned short* ps = &proj_bf[(size_t)(r.x & 0xFFFFu) * FDIM];
        a0 += bf2f((unsigned short)(r.x >> 16)) * bf2f(ps[lane]);
        a1 += bf2f((unsigned short)(r.y & 0xFFFFu)) * bf2f(ps[64 + lane]);
        a2 += bf2f((unsigned short)(r.y >> 16)) * bf2f(ps[128 + lane]);
      }
      const float4 inv = inv4[n];
      float r0 = a0 * inv.x + bg0;
      float r1 = a1 * inv.y + bg1;
      float r2 = a2 * inv.z + bg2;
      h2 = (fmaxf(r0, 0.f) + fmaxf(r1, 0.f) + fmaxf(r2, 0.f)) * (1.f / 3.f);
    }
    int byte = ln * 128 + lane * 2;
    byte ^= (ln & 7) << 4;                      // bank-conflict swizzle
    *reinterpret_cast<unsigned short*>(h2b + byte) = f2bf(h2);
  }
  __syncthreads();

  // ---- MLP: relu(h2@W1+b1)@W2+b2, A from swizzled LDS ----------------------
  const int r = lane & 15;
  const int q = lane >> 4;
  const int kg = q * 8;
  const int rw0 = base + wave * 16;

  f32x4 acc1[8];
#pragma unroll
  for (int c = 0; c < 8; ++c) acc1[c] = (f32x4){0.f, 0.f, 0.f, 0.f};

#pragma unroll
  for (int ks = 0; ks < 2; ++ks) {
    int abyte = (wave * 16 + r) * 128 + (kg + ks * 32) * 2;
    abyte ^= (r & 7) << 4;                      // matches write swizzle
    bf16x8 a = *reinterpret_cast<const bf16x8*>(h2b + abyte);
#pragma unroll
    for (int c = 0; c < 8; ++c) {
      bf16x8 b = *reinterpret_cast<const bf16x8*>(&W1t[(size_t)(c * 16 + r) * 64 + kg + ks * 32]);
      acc1[c] = __builtin_amdgcn_mfma_f32_16x16x32_bf16(a, b, acc1[c], 0, 0, 0);
    }
  }
#pragma unroll
  for (int c = 0; c < 8; ++c) {
    float bb = b1[c * 16 + r];
#pragma unroll
    for (int i = 0; i < 4; ++i) {
      float z = acc1[c][i] + bb;
      z = z > 0.f ? z : 0.f;
      z_lds[(wave * 16 + 4 * q + i) * 128 + c * 16 + r] = f2bf(z);
    }
  }
  __syncthreads();

  f32x4 acc2 = (f32x4){0.f, 0.f, 0.f, 0.f};
#pragma unroll
  for (int ks = 0; ks < 4; ++ks) {
    bf16x8 a = *reinterpret_cast<const bf16x8*>(&z_lds[(wave * 16 + r) * 128 + kg + ks * 32]);
    bf16x8 b = *reinterpret_cast<const bf16x8*>(&W2t[(size_t)r * 128 + kg + ks * 32]);
    acc2 = __builtin_amdgcn_mfma_f32_16x16x32_bf16(a, b, acc2, 0, 0, 0);
  }
  const int part = blockIdx.x & (NPART - 1);
  float bb2 = b2[r];
#pragma unroll
  for (int i = 0; i < 4; ++i) {
    int row = rw0 + 4 * q + i;
    if (row < N) {
      int g = gid[row];
      atomicAdd(&sums_priv[(part * NGRAPH + g) * 16 + r], acc2[i] + bb2);
      if (r == 0) atomicAdd(&counts_priv[part * NGRAPH + g], 1.f);
    }
  }
}

// ---------------- reduce privatized graph sums -> output --------------------
__global__ void finalize_kernel(const float* __restrict__ sums_priv,
                                const float* __restrict__ counts_priv,
                                float* __restrict__ out)
{
  int j = threadIdx.x;            // 0..1023  (g*16 + col)
  int g = j >> 4;
  float s = 0.f, c = 0.f;
  for (int p = 0; p < NPART; ++p) {
    s += sums_priv[p * NGRAPH * 16 + j];
    c += counts_priv[p * NGRAPH + g];
  }
  out[j] = s / fmaxf(c, 1.f);
}

extern "C" void kernel_launch(void* const* d_in, const int* in_sizes, int n_in,
                              void* d_out, int out_size, void* d_ws, size_t ws_size,
                              hipStream_t stream)
{
  const int*   h0  = (const int*)  d_in[0];
  const int*   src = (const int*)  d_in[1];
  const int*   dst = (const int*)  d_in[2];
  const int*   gid = (const int*)  d_in[3];
  const float* emb = (const float*)d_in[4];
  const float* Wfc = (const float*)d_in[5];
  const float* al  = (const float*)d_in[6];
  const float* ar  = (const float*)d_in[7];
  const float* bg  = (const float*)d_in[8];
  const float* W1  = (const float*)d_in[9];
  const float* b1  = (const float*)d_in[10];
  const float* W2  = (const float*)d_in[11];
  const float* b2  = (const float*)d_in[12];
  float* out = (float*)d_out;

  char* ws = (char*)d_ws;
  size_t off = 0;
  auto alloc = [&](size_t bytes) -> void* {
    off = (off + 255) & ~(size_t)255;
    void* p = ws + off;
    off += bytes;
    return p;
  };
  // contiguous zero region: cnt | sums | cnts  (one memset)
  const size_t CNT_B  = (size_t)NNODES * 4;                 // 400000
  const size_t CNT_BP = (CNT_B + 255) & ~(size_t)255;       // 400128
  const size_t SUMS_B = (size_t)NPART * NGRAPH * 16 * 4;    // 262144
  const size_t ZB     = CNT_BP + SUMS_B + (size_t)NPART * NGRAPH * 4;
  char*  zero_base = (char*)alloc(ZB);
  int*   cnt  = (int*)zero_base;
  float* sums = (float*)(zero_base + CNT_BP);
  float* cnts = (float*)(zero_base + CNT_BP + SUMS_B);

  unsigned short* Wt      = (unsigned short*)alloc((size_t)FDIM * HDIM * 2);
  unsigned short* W1t     = (unsigned short*)alloc((size_t)128 * 64 * 2);
  unsigned short* W2t     = (unsigned short*)alloc((size_t)16 * 128 * 2);
  unsigned short* proj_bf = (unsigned short*)alloc((size_t)VOCAB * FDIM * 2);
  unsigned short* recs16  = (unsigned short*)alloc((size_t)NEDGES * 2);
  unsigned short* rank16  = (unsigned short*)alloc((size_t)NEDGES * 2);
  uint2*  wrec   = (uint2*) alloc((size_t)NEDGES * 8);
  float4* elv4   = (float4*)alloc((size_t)VOCAB * 16);
  float4* erv4   = (float4*)alloc((size_t)VOCAB * 16);
  float4* inv4   = (float4*)alloc((size_t)NNODES * 16);
  int*    offs   = (int*)   alloc((size_t)(NNODES + 1) * 4);

  hipMemsetAsync(zero_base, 0, ZB, stream);

  conv_hist_kernel<<<CONV_BLOCKS + HIST_BLOCKS, 256, 0, stream>>>(
      Wfc, W1, W2, Wt, W1t, W2t, dst, cnt, rank16);
  scan_fused_kernel<<<1, 1024, 0, stream>>>(cnt, offs, NNODES);
  proj_scatter_kernel<<<PROJ_BLOCKS + HIST_BLOCKS, 256, 0, stream>>>(
      emb, Wt, al, ar, proj_bf, elv4, erv4,
      src, dst, h0, rank16, offs, recs16);
  wexp_kernel<<<(NNODES + 3) / 4, 256, 0, stream>>>(recs16, offs, h0, elv4, erv4,
                                                    wrec, inv4, NNODES);
  aggmlp_kernel<<<(NNODES + 63) / 64, 256, 0, stream>>>(
      wrec, offs, inv4, proj_bf, bg, W1t, b1, W2t, b2, gid, sums, cnts, NNODES);
  finalize_kernel<<<1, 1024, 0, stream>>>(sums, cnts, out);
}

// Round 10
// 477.756 us; speedup vs baseline: 1.1113x; 1.1113x over previous
//
#include <hip/hip_runtime.h>
#include <hip/hip_bf16.h>

#define NNODES 100000
#define NEDGES 1600000
#define VOCAB 50000
#define HDIM 256
#define ADIM 64
#define NHEADS 3
#define FDIM 192   // NHEADS*ADIM
#define NGRAPH 64
#define NPART 64

#define CONV_ELEMS (HDIM * FDIM + 128 * 64 + 16 * 128)   // 59392
#define CONV_BLOCKS ((CONV_ELEMS + 255) / 256)            // 232
#define HIST_BLOCKS ((NEDGES + 255) / 256)                // 6250
#define PROJ_BLOCKS ((VOCAB + 63) / 64)                   // 782

typedef __attribute__((ext_vector_type(8))) short bf16x8;  // 8 bf16 = 4 VGPRs
typedef __attribute__((ext_vector_type(4))) float f32x4;

__device__ __forceinline__ float bf2f(unsigned short u) {
  return __uint_as_float((unsigned int)u << 16);
}
__device__ __forceinline__ unsigned short f2bf(float f) {
  unsigned int u = __float_as_uint(f);
  u += 0x7FFFu + ((u >> 16) & 1u);   // round-nearest-even
  return (unsigned short)(u >> 16);
}

// ---- fused: weight transpose/cast (blocks 0..231)  ||  hist+rank (rest) ----
__global__ __launch_bounds__(256) void conv_hist_kernel(
    const float* __restrict__ Wfc, const float* __restrict__ W1,
    const float* __restrict__ W2, unsigned short* __restrict__ Wt,
    unsigned short* __restrict__ W1t, unsigned short* __restrict__ W2t,
    const int* __restrict__ dst, int* __restrict__ cnt,
    unsigned short* __restrict__ rank16)
{
  if (blockIdx.x < CONV_BLOCKS) {
    int i = blockIdx.x * 256 + threadIdx.x;
    if (i < HDIM * FDIM) {
      int c = i / HDIM, k = i % HDIM;
      Wt[i] = f2bf(Wfc[(size_t)k * FDIM + c]);
    } else if (i < HDIM * FDIM + 128 * 64) {
      int j = i - HDIM * FDIM;
      int c = j / 64, k = j % 64;
      W1t[j] = f2bf(W1[(size_t)k * 128 + c]);
    } else if (i < CONV_ELEMS) {
      int j = i - HDIM * FDIM - 128 * 64;
      int c = j / 128, k = j % 128;
      W2t[j] = f2bf(W2[(size_t)k * 16 + c]);
    }
  } else {
    int e = (blockIdx.x - CONV_BLOCKS) * 256 + threadIdx.x;
    if (e < NEDGES) rank16[e] = (unsigned short)atomicAdd(&cnt[dst[e]], 1);
  }
}

// ---- single-block exclusive scan of cnt[0..N) -> offs[0..N] ---------------
__global__ __launch_bounds__(1024) void scan_fused_kernel(
    const int* __restrict__ cnt, int* __restrict__ offs, int n)
{
  __shared__ int sd[1024];
  const int C = 98;                  // 98*1024 >= 100000
  int t = threadIdx.x;
  int start = t * C, end = start + C;
  if (start > n) start = n;
  if (end > n) end = n;
  int s = 0;
  for (int i = start; i < end; ++i) s += cnt[i];
  sd[t] = s;
  __syncthreads();
  for (int o = 1; o < 1024; o <<= 1) {
    int v = (t >= o) ? sd[t - o] : 0;
    __syncthreads();
    sd[t] += v;
    __syncthreads();
  }
  int run = sd[t] - s;               // exclusive prefix of this chunk
  for (int i = start; i < end; ++i) {
    offs[i] = run;
    run += cnt[i];
  }
  if (t == 1023) offs[n] = run;      // == total
}

// ---- fused: proj GEMM + attn dots (blocks 0..781)  ||  scatter (rest) ------
__global__ __launch_bounds__(256) void proj_scatter_kernel(
    const float* __restrict__ emb,              // [V][256] f32
    const unsigned short* __restrict__ Wt,      // [192][256] bf16
    const float* __restrict__ attn_l, const float* __restrict__ attn_r,
    unsigned short* __restrict__ proj_bf,       // [V][192]
    float4* __restrict__ elv4, float4* __restrict__ erv4,
    const int* __restrict__ src, const int* __restrict__ dst,
    const int* __restrict__ h0, const unsigned short* __restrict__ rank16,
    const int* __restrict__ offs, unsigned short* __restrict__ recs16)
{
  if (blockIdx.x >= PROJ_BLOCKS) {
    int e = (blockIdx.x - PROJ_BLOCKS) * 256 + threadIdx.x;
    if (e < NEDGES) {
      int p = offs[dst[e]] + (int)rank16[e];
      recs16[p] = (unsigned short)h0[src[e]];
    }
    return;
  }
  const int wave = threadIdx.x >> 6;
  const int lane = threadIdx.x & 63;
  const int row0 = blockIdx.x * 64 + wave * 16;
  const int cb = lane & 15;
  const int q  = lane >> 4;
  int arow = row0 + cb;
  if (arow >= VOCAB) arow = VOCAB - 1;          // clamp loads; stores guarded
  const int kgrp = q * 8;

  f32x4 acc[12];
#pragma unroll
  for (int c = 0; c < 12; ++c) acc[c] = (f32x4){0.f, 0.f, 0.f, 0.f};

  const float* arow_p = &emb[(size_t)arow * HDIM + kgrp];
  const unsigned short* bcol_p = &Wt[(size_t)cb * HDIM + kgrp];

#pragma unroll
  for (int ks = 0; ks < 8; ++ks) {
    float4 f0 = *reinterpret_cast<const float4*>(arow_p + ks * 32);
    float4 f1 = *reinterpret_cast<const float4*>(arow_p + ks * 32 + 4);
    bf16x8 a;
    a[0] = (short)f2bf(f0.x); a[1] = (short)f2bf(f0.y);
    a[2] = (short)f2bf(f0.z); a[3] = (short)f2bf(f0.w);
    a[4] = (short)f2bf(f1.x); a[5] = (short)f2bf(f1.y);
    a[6] = (short)f2bf(f1.z); a[7] = (short)f2bf(f1.w);
#pragma unroll
    for (int c = 0; c < 12; ++c) {
      bf16x8 b = *reinterpret_cast<const bf16x8*>(bcol_p + (size_t)c * 16 * HDIM + ks * 32);
      acc[c] = __builtin_amdgcn_mfma_f32_16x16x32_bf16(a, b, acc[c], 0, 0, 0);
    }
  }

  const int rb = row0 + 4 * q;
#pragma unroll
  for (int i = 0; i < 4; ++i) {
    int r = rb + i;
    if (r < VOCAB) {
#pragma unroll
      for (int c = 0; c < 12; ++c)
        proj_bf[(size_t)r * FDIM + c * 16 + cb] = f2bf(acc[c][i]);
    }
  }

  // fused attention dots
  float al_v[12], ar_v[12];
#pragma unroll
  for (int c = 0; c < 12; ++c) {
    al_v[c] = attn_l[c * 16 + cb];
    ar_v[c] = attn_r[c * 16 + cb];
  }
  float elp[4][3], erp[4][3];
#pragma unroll
  for (int i = 0; i < 4; ++i)
#pragma unroll
    for (int h = 0; h < 3; ++h) {
      float sl = 0.f, sr = 0.f;
#pragma unroll
      for (int cc = 0; cc < 4; ++cc) {
        float v = acc[h * 4 + cc][i];
        sl += v * al_v[h * 4 + cc];
        sr += v * ar_v[h * 4 + cc];
      }
      elp[i][h] = sl; erp[i][h] = sr;
    }
#pragma unroll
  for (int s = 8; s > 0; s >>= 1) {
#pragma unroll
    for (int i = 0; i < 4; ++i)
#pragma unroll
      for (int h = 0; h < 3; ++h) {
        elp[i][h] += __shfl_xor(elp[i][h], s, 64);
        erp[i][h] += __shfl_xor(erp[i][h], s, 64);
      }
  }
  if (cb == 0) {
#pragma unroll
    for (int i = 0; i < 4; ++i) {
      int r = rb + i;
      if (r < VOCAB) {
        elv4[r] = make_float4(elp[i][0], elp[i][1], elp[i][2], 0.f);
        erv4[r] = make_float4(erp[i][0], erp[i][1], erp[i][2], 0.f);
      }
    }
  }
}

// ---- per-node weights: w = exp(leaky(el+er)) once per EDGE (r7 version) ----
__global__ __launch_bounds__(256) void wexp_kernel(
    const unsigned short* __restrict__ recs16, const int* __restrict__ offs,
    const int* __restrict__ h0,
    const float4* __restrict__ elv4, const float4* __restrict__ erv4,
    uint2* __restrict__ wrec, float4* __restrict__ inv4, int N)
{
  int n = blockIdx.x * 256 + threadIdx.x;
  if (n >= N) return;
  const float4 ero = erv4[h0[n]];
  int lo = offs[n], hi = offs[n + 1];
  float d0 = 0.f, d1 = 0.f, d2 = 0.f;
  for (int p = lo; p < hi; ++p) {
    unsigned v = recs16[p];
    float4 ev = elv4[v];
    float e0 = ev.x + ero.x, e1 = ev.y + ero.y, e2 = ev.z + ero.z;
    e0 = e0 > 0.f ? e0 : 0.2f * e0;   // leaky_relu 0.2
    e1 = e1 > 0.f ? e1 : 0.2f * e1;
    e2 = e2 > 0.f ? e2 : 0.2f * e2;
    unsigned short u0 = f2bf(__expf(e0));
    unsigned short u1 = f2bf(__expf(e1));
    unsigned short u2 = f2bf(__expf(e2));
    d0 += bf2f(u0); d1 += bf2f(u1); d2 += bf2f(u2);   // sum ROUNDED w
    wrec[p] = make_uint2(v | ((unsigned)u0 << 16),
                         (unsigned)u1 | ((unsigned)u2 << 16));
  }
  inv4[n] = make_float4(d0 > 0.f ? 1.f / d0 : 0.f,
                        d1 > 0.f ? 1.f / d1 : 0.f,
                        d2 > 0.f ? 1.f / d2 : 0.f, 0.f);
}

// ---- per-node aggregation: pure gather+FMA (r7 version) --------------------
__global__ __launch_bounds__(256) void aggregate_kernel(
    const uint2* __restrict__ wrec, const int* __restrict__ offs,
    const float4* __restrict__ inv4,
    const unsigned short* __restrict__ proj_bf, const float* __restrict__ bias_gat,
    unsigned short* __restrict__ h2bf, int N)
{
  int lane = threadIdx.x & 63;
  int n = blockIdx.x * 4 + (threadIdx.x >> 6);
  if (n >= N) return;
  int lo = offs[n], hi = offs[n + 1];
  float a0 = 0.f, a1 = 0.f, a2 = 0.f;

  int i = lo;
  for (; i + 4 <= hi; i += 4) {
    uint2 r[4];
#pragma unroll
    for (int j = 0; j < 4; ++j) r[j] = wrec[i + j];
    const unsigned short* ps[4];
#pragma unroll
    for (int j = 0; j < 4; ++j)
      ps[j] = &proj_bf[(size_t)(r[j].x & 0xFFFFu) * FDIM];
    float g0[4], g1[4], g2[4];
#pragma unroll
    for (int j = 0; j < 4; ++j) {       // 12 independent gathers in flight
      g0[j] = bf2f(ps[j][lane]);
      g1[j] = bf2f(ps[j][64 + lane]);
      g2[j] = bf2f(ps[j][128 + lane]);
    }
#pragma unroll
    for (int j = 0; j < 4; ++j) {
      a0 += bf2f((unsigned short)(r[j].x >> 16)) * g0[j];
      a1 += bf2f((unsigned short)(r[j].y & 0xFFFFu)) * g1[j];
      a2 += bf2f((unsigned short)(r[j].y >> 16)) * g2[j];
    }
  }
  for (; i < hi; ++i) {
    uint2 r = wrec[i];
    const unsigned short* ps = &proj_bf[(size_t)(r.x & 0xFFFFu) * FDIM];
    a0 += bf2f((unsigned short)(r.x >> 16)) * bf2f(ps[lane]);
    a1 += bf2f((unsigned short)(r.y & 0xFFFFu)) * bf2f(ps[64 + lane]);
    a2 += bf2f((unsigned short)(r.y >> 16)) * bf2f(ps[128 + lane]);
  }

  const float4 inv = inv4[n];
  float r0 = a0 * inv.x + bias_gat[lane];
  float r1 = a1 * inv.y + bias_gat[64 + lane];
  float r2 = a2 * inv.z + bias_gat[128 + lane];
  float h2 = (fmaxf(r0, 0.f) + fmaxf(r1, 0.f) + fmaxf(r2, 0.f)) * (1.f / 3.f);
  h2bf[(size_t)n * 64 + lane] = f2bf(h2);
}

// ---- MLP via MFMA: relu(h2@W1+b1)@W2+b2 + graph atomics (r7 version) -------
__global__ __launch_bounds__(256) void post_mfma_kernel(
    const unsigned short* __restrict__ h2bf,   // [N][64]
    const unsigned short* __restrict__ W1t,    // [128][64]
    const float* __restrict__ b1,
    const unsigned short* __restrict__ W2t,    // [16][128]
    const float* __restrict__ b2, const int* __restrict__ gid,
    float* __restrict__ sums_priv, float* __restrict__ counts_priv, int N)
{
  __shared__ unsigned short z_lds[64 * 128];
  const int wave = threadIdx.x >> 6;
  const int lane = threadIdx.x & 63;
  const int r = lane & 15;
  const int q = lane >> 4;
  const int kg = q * 8;
  const int rw0 = blockIdx.x * 64 + wave * 16;

  int arow = rw0 + r;
  if (arow >= N) arow = N - 1;       // clamp loads; stores guarded

  f32x4 acc1[8];
#pragma unroll
  for (int c = 0; c < 8; ++c) acc1[c] = (f32x4){0.f, 0.f, 0.f, 0.f};

#pragma unroll
  for (int ks = 0; ks < 2; ++ks) {
    bf16x8 a = *reinterpret_cast<const bf16x8*>(&h2bf[(size_t)arow * 64 + kg + ks * 32]);
#pragma unroll
    for (int c = 0; c < 8; ++c) {
      bf16x8 b = *reinterpret_cast<const bf16x8*>(&W1t[(size_t)(c * 16 + r) * 64 + kg + ks * 32]);
      acc1[c] = __builtin_amdgcn_mfma_f32_16x16x32_bf16(a, b, acc1[c], 0, 0, 0);
    }
  }
#pragma unroll
  for (int c = 0; c < 8; ++c) {
    float bb = b1[c * 16 + r];
#pragma unroll
    for (int i = 0; i < 4; ++i) {
      float z = acc1[c][i] + bb;
      z = z > 0.f ? z : 0.f;
      z_lds[(wave * 16 + 4 * q + i) * 128 + c * 16 + r] = f2bf(z);
    }
  }
  __syncthreads();

  f32x4 acc2 = (f32x4){0.f, 0.f, 0.f, 0.f};
#pragma unroll
  for (int ks = 0; ks < 4; ++ks) {
    bf16x8 a = *reinterpret_cast<const bf16x8*>(&z_lds[(wave * 16 + r) * 128 + kg + ks * 32]);
    bf16x8 b = *reinterpret_cast<const bf16x8*>(&W2t[(size_t)r * 128 + kg + ks * 32]);
    acc2 = __builtin_amdgcn_mfma_f32_16x16x32_bf16(a, b, acc2, 0, 0, 0);
  }
  const int part = blockIdx.x & (NPART - 1);
  float bb2 = b2[r];
#pragma unroll
  for (int i = 0; i < 4; ++i) {
    int row = rw0 + 4 * q + i;
    if (row < N) {
      int g = gid[row];
      atomicAdd(&sums_priv[(part * NGRAPH + g) * 16 + r], acc2[i] + bb2);
      if (r == 0) atomicAdd(&counts_priv[part * NGRAPH + g], 1.f);
    }
  }
}

// ---------------- reduce privatized graph sums -> output --------------------
__global__ void finalize_kernel(const float* __restrict__ sums_priv,
                                const float* __restrict__ counts_priv,
                                float* __restrict__ out)
{
  int j = threadIdx.x;            // 0..1023  (g*16 + col)
  int g = j >> 4;
  float s = 0.f, c = 0.f;
  for (int p = 0; p < NPART; ++p) {
    s += sums_priv[p * NGRAPH * 16 + j];
    c += counts_priv[p * NGRAPH + g];
  }
  out[j] = s / fmaxf(c, 1.f);
}

extern "C" void kernel_launch(void* const* d_in, const int* in_sizes, int n_in,
                              void* d_out, int out_size, void* d_ws, size_t ws_size,
                              hipStream_t stream)
{
  const int*   h0  = (const int*)  d_in[0];
  const int*   src = (const int*)  d_in[1];
  const int*   dst = (const int*)  d_in[2];
  const int*   gid = (const int*)  d_in[3];
  const float* emb = (const float*)d_in[4];
  const float* Wfc = (const float*)d_in[5];
  const float* al  = (const float*)d_in[6];
  const float* ar  = (const float*)d_in[7];
  const float* bg  = (const float*)d_in[8];
  const float* W1  = (const float*)d_in[9];
  const float* b1  = (const float*)d_in[10];
  const float* W2  = (const float*)d_in[11];
  const float* b2  = (const float*)d_in[12];
  float* out = (float*)d_out;

  char* ws = (char*)d_ws;
  size_t off = 0;
  auto alloc = [&](size_t bytes) -> void* {
    off = (off + 255) & ~(size_t)255;
    void* p = ws + off;
    off += bytes;
    return p;
  };
  // contiguous zero region: cnt | sums | cnts  (one memset)
  const size_t CNT_B  = (size_t)NNODES * 4;                 // 400000
  const size_t CNT_BP = (CNT_B + 255) & ~(size_t)255;       // 400128
  const size_t SUMS_B = (size_t)NPART * NGRAPH * 16 * 4;    // 262144
  const size_t ZB     = CNT_BP + SUMS_B + (size_t)NPART * NGRAPH * 4;
  char*  zero_base = (char*)alloc(ZB);
  int*   cnt  = (int*)zero_base;
  float* sums = (float*)(zero_base + CNT_BP);
  float* cnts = (float*)(zero_base + CNT_BP + SUMS_B);

  unsigned short* Wt      = (unsigned short*)alloc((size_t)FDIM * HDIM * 2);
  unsigned short* W1t     = (unsigned short*)alloc((size_t)128 * 64 * 2);
  unsigned short* W2t     = (unsigned short*)alloc((size_t)16 * 128 * 2);
  unsigned short* proj_bf = (unsigned short*)alloc((size_t)VOCAB * FDIM * 2);
  unsigned short* h2bf    = (unsigned short*)alloc((size_t)NNODES * 64 * 2);
  unsigned short* recs16  = (unsigned short*)alloc((size_t)NEDGES * 2);
  unsigned short* rank16  = (unsigned short*)alloc((size_t)NEDGES * 2);
  uint2*  wrec   = (uint2*) alloc((size_t)NEDGES * 8);
  float4* elv4   = (float4*)alloc((size_t)VOCAB * 16);
  float4* erv4   = (float4*)alloc((size_t)VOCAB * 16);
  float4* inv4   = (float4*)alloc((size_t)NNODES * 16);
  int*    offs   = (int*)   alloc((size_t)(NNODES + 1) * 4);

  hipMemsetAsync(zero_base, 0, ZB, stream);

  conv_hist_kernel<<<CONV_BLOCKS + HIST_BLOCKS, 256, 0, stream>>>(
      Wfc, W1, W2, Wt, W1t, W2t, dst, cnt, rank16);
  scan_fused_kernel<<<1, 1024, 0, stream>>>(cnt, offs, NNODES);
  proj_scatter_kernel<<<PROJ_BLOCKS + HIST_BLOCKS, 256, 0, stream>>>(
      emb, Wt, al, ar, proj_bf, elv4, erv4,
      src, dst, h0, rank16, offs, recs16);
  wexp_kernel<<<(NNODES + 255) / 256, 256, 0, stream>>>(recs16, offs, h0, elv4, erv4,
                                                        wrec, inv4, NNODES);
  aggregate_kernel<<<(NNODES + 3) / 4, 256, 0, stream>>>(wrec, offs, inv4, proj_bf,
                                                         bg, h2bf, NNODES);
  post_mfma_kernel<<<(NNODES + 63) / 64, 256, 0, stream>>>(h2bf, W1t, b1, W2t, b2, gid,
                                                           sums, cnts, NNODES);
  finalize_kernel<<<1, 1024, 0, stream>>>(sums, cnts, out);
}

// Round 11
// 335.428 us; speedup vs baseline: 1.5829x; 1.4243x over previous
//
#include <hip/hip_runtime.h>
#include <hip/hip_bf16.h>

#define NNODES 100000
#define NEDGES 1600000
#define VOCAB 50000
#define HDIM 256
#define ADIM 64
#define NHEADS 3
#define FDIM 192   // NHEADS*ADIM
#define NGRAPH 64
#define NPART 64

#define CONV_ELEMS (HDIM * FDIM + 128 * 64 + 16 * 128)   // 59392
#define CONV_BLOCKS ((CONV_ELEMS + 255) / 256)            // 232
#define HIST_BLOCKS ((NEDGES + 255) / 256)                // 6250
#define PROJ_BLOCKS ((VOCAB + 63) / 64)                   // 782

typedef __attribute__((ext_vector_type(8))) short bf16x8;  // 8 bf16 = 4 VGPRs
typedef __attribute__((ext_vector_type(4))) float f32x4;

__device__ __forceinline__ float bf2f(unsigned short u) {
  return __uint_as_float((unsigned int)u << 16);
}
__device__ __forceinline__ unsigned short f2bf(float f) {
  unsigned int u = __float_as_uint(f);
  u += 0x7FFFu + ((u >> 16) & 1u);   // round-nearest-even
  return (unsigned short)(u >> 16);
}

// ---- fused: weight transpose/cast (blocks 0..231)  ||  hist+rank (rest) ----
__global__ __launch_bounds__(256) void conv_hist_kernel(
    const float* __restrict__ Wfc, const float* __restrict__ W1,
    const float* __restrict__ W2, unsigned short* __restrict__ Wt,
    unsigned short* __restrict__ W1t, unsigned short* __restrict__ W2t,
    const int* __restrict__ dst, int* __restrict__ cnt,
    unsigned short* __restrict__ rank16)
{
  if (blockIdx.x < CONV_BLOCKS) {
    int i = blockIdx.x * 256 + threadIdx.x;
    if (i < HDIM * FDIM) {
      int c = i / HDIM, k = i % HDIM;
      Wt[i] = f2bf(Wfc[(size_t)k * FDIM + c]);
    } else if (i < HDIM * FDIM + 128 * 64) {
      int j = i - HDIM * FDIM;
      int c = j / 64, k = j % 64;
      W1t[j] = f2bf(W1[(size_t)k * 128 + c]);
    } else if (i < CONV_ELEMS) {
      int j = i - HDIM * FDIM - 128 * 64;
      int c = j / 128, k = j % 128;
      W2t[j] = f2bf(W2[(size_t)k * 16 + c]);
    }
  } else {
    int e = (blockIdx.x - CONV_BLOCKS) * 256 + threadIdx.x;
    if (e < NEDGES) rank16[e] = (unsigned short)atomicAdd(&cnt[dst[e]], 1);
  }
}

// ---- 3-kernel scan (r7 version): parallel across 98 blocks -----------------
__global__ __launch_bounds__(256) void scan_sum_kernel(
    const int* __restrict__ cnt, int* __restrict__ bsum, int n)
{
  __shared__ int red[256];
  int t = threadIdx.x;
  int base = blockIdx.x * 1024 + t * 4;
  int s = 0;
#pragma unroll
  for (int j = 0; j < 4; ++j) if (base + j < n) s += cnt[base + j];
  red[t] = s;
  __syncthreads();
  for (int o = 128; o > 0; o >>= 1) {
    if (t < o) red[t] += red[t + o];
    __syncthreads();
  }
  if (t == 0) bsum[blockIdx.x] = red[0];
}

__global__ void scan_bsum_kernel(int* bsum, int nb)
{
  if (threadIdx.x == 0 && blockIdx.x == 0) {
    int acc = 0;
    for (int i = 0; i < nb; ++i) { int v = bsum[i]; bsum[i] = acc; acc += v; }
  }
}

__global__ __launch_bounds__(256) void scan_write_kernel(
    const int* __restrict__ cnt, const int* __restrict__ bsum,
    int* __restrict__ offs, int n, int total)
{
  __shared__ int sd[256];
  int t = threadIdx.x;
  int base = blockIdx.x * 1024 + t * 4;
  int c[4];
  int ts = 0;
#pragma unroll
  for (int j = 0; j < 4; ++j) { c[j] = (base + j < n) ? cnt[base + j] : 0; ts += c[j]; }
  sd[t] = ts;
  __syncthreads();
  for (int o = 1; o < 256; o <<= 1) {
    int v = (t >= o) ? sd[t - o] : 0;
    __syncthreads();
    sd[t] += v;
    __syncthreads();
  }
  int run = sd[t] - ts + bsum[blockIdx.x];
#pragma unroll
  for (int j = 0; j < 4; ++j) {
    if (base + j < n) offs[base + j] = run;
    run += c[j];
  }
  if (blockIdx.x == 0 && t == 0) offs[n] = total;
}

// ---- fused: proj GEMM + attn dots (blocks 0..781)  ||  scatter (rest) ------
__global__ __launch_bounds__(256) void proj_scatter_kernel(
    const float* __restrict__ emb,              // [V][256] f32
    const unsigned short* __restrict__ Wt,      // [192][256] bf16
    const float* __restrict__ attn_l, const float* __restrict__ attn_r,
    unsigned short* __restrict__ proj_bf,       // [V][192]
    float4* __restrict__ elv4, float4* __restrict__ erv4,
    const int* __restrict__ src, const int* __restrict__ dst,
    const int* __restrict__ h0, const unsigned short* __restrict__ rank16,
    const int* __restrict__ offs, unsigned short* __restrict__ recs16)
{
  if (blockIdx.x >= PROJ_BLOCKS) {
    int e = (blockIdx.x - PROJ_BLOCKS) * 256 + threadIdx.x;
    if (e < NEDGES) {
      int p = offs[dst[e]] + (int)rank16[e];
      recs16[p] = (unsigned short)h0[src[e]];
    }
    return;
  }
  const int wave = threadIdx.x >> 6;
  const int lane = threadIdx.x & 63;
  const int row0 = blockIdx.x * 64 + wave * 16;
  const int cb = lane & 15;
  const int q  = lane >> 4;
  int arow = row0 + cb;
  if (arow >= VOCAB) arow = VOCAB - 1;          // clamp loads; stores guarded
  const int kgrp = q * 8;

  f32x4 acc[12];
#pragma unroll
  for (int c = 0; c < 12; ++c) acc[c] = (f32x4){0.f, 0.f, 0.f, 0.f};

  const float* arow_p = &emb[(size_t)arow * HDIM + kgrp];
  const unsigned short* bcol_p = &Wt[(size_t)cb * HDIM + kgrp];

#pragma unroll
  for (int ks = 0; ks < 8; ++ks) {
    float4 f0 = *reinterpret_cast<const float4*>(arow_p + ks * 32);
    float4 f1 = *reinterpret_cast<const float4*>(arow_p + ks * 32 + 4);
    bf16x8 a;
    a[0] = (short)f2bf(f0.x); a[1] = (short)f2bf(f0.y);
    a[2] = (short)f2bf(f0.z); a[3] = (short)f2bf(f0.w);
    a[4] = (short)f2bf(f1.x); a[5] = (short)f2bf(f1.y);
    a[6] = (short)f2bf(f1.z); a[7] = (short)f2bf(f1.w);
#pragma unroll
    for (int c = 0; c < 12; ++c) {
      bf16x8 b = *reinterpret_cast<const bf16x8*>(bcol_p + (size_t)c * 16 * HDIM + ks * 32);
      acc[c] = __builtin_amdgcn_mfma_f32_16x16x32_bf16(a, b, acc[c], 0, 0, 0);
    }
  }

  const int rb = row0 + 4 * q;
#pragma unroll
  for (int i = 0; i < 4; ++i) {
    int r = rb + i;
    if (r < VOCAB) {
#pragma unroll
      for (int c = 0; c < 12; ++c)
        proj_bf[(size_t)r * FDIM + c * 16 + cb] = f2bf(acc[c][i]);
    }
  }

  // fused attention dots
  float al_v[12], ar_v[12];
#pragma unroll
  for (int c = 0; c < 12; ++c) {
    al_v[c] = attn_l[c * 16 + cb];
    ar_v[c] = attn_r[c * 16 + cb];
  }
  float elp[4][3], erp[4][3];
#pragma unroll
  for (int i = 0; i < 4; ++i)
#pragma unroll
    for (int h = 0; h < 3; ++h) {
      float sl = 0.f, sr = 0.f;
#pragma unroll
      for (int cc = 0; cc < 4; ++cc) {
        float v = acc[h * 4 + cc][i];
        sl += v * al_v[h * 4 + cc];
        sr += v * ar_v[h * 4 + cc];
      }
      elp[i][h] = sl; erp[i][h] = sr;
    }
#pragma unroll
  for (int s = 8; s > 0; s >>= 1) {
#pragma unroll
    for (int i = 0; i < 4; ++i)
#pragma unroll
      for (int h = 0; h < 3; ++h) {
        elp[i][h] += __shfl_xor(elp[i][h], s, 64);
        erp[i][h] += __shfl_xor(erp[i][h], s, 64);
      }
  }
  if (cb == 0) {
#pragma unroll
    for (int i = 0; i < 4; ++i) {
      int r = rb + i;
      if (r < VOCAB) {
        elv4[r] = make_float4(elp[i][0], elp[i][1], elp[i][2], 0.f);
        erv4[r] = make_float4(erp[i][0], erp[i][1], erp[i][2], 0.f);
      }
    }
  }
}

// ---- per-node weights: w = exp(leaky(el+er)) once per EDGE (r7 version) ----
__global__ __launch_bounds__(256) void wexp_kernel(
    const unsigned short* __restrict__ recs16, const int* __restrict__ offs,
    const int* __restrict__ h0,
    const float4* __restrict__ elv4, const float4* __restrict__ erv4,
    uint2* __restrict__ wrec, float4* __restrict__ inv4, int N)
{
  int n = blockIdx.x * 256 + threadIdx.x;
  if (n >= N) return;
  const float4 ero = erv4[h0[n]];
  int lo = offs[n], hi = offs[n + 1];
  float d0 = 0.f, d1 = 0.f, d2 = 0.f;
  for (int p = lo; p < hi; ++p) {
    unsigned v = recs16[p];
    float4 ev = elv4[v];
    float e0 = ev.x + ero.x, e1 = ev.y + ero.y, e2 = ev.z + ero.z;
    e0 = e0 > 0.f ? e0 : 0.2f * e0;   // leaky_relu 0.2
    e1 = e1 > 0.f ? e1 : 0.2f * e1;
    e2 = e2 > 0.f ? e2 : 0.2f * e2;
    unsigned short u0 = f2bf(__expf(e0));
    unsigned short u1 = f2bf(__expf(e1));
    unsigned short u2 = f2bf(__expf(e2));
    d0 += bf2f(u0); d1 += bf2f(u1); d2 += bf2f(u2);   // sum ROUNDED w
    wrec[p] = make_uint2(v | ((unsigned)u0 << 16),
                         (unsigned)u1 | ((unsigned)u2 << 16));
  }
  inv4[n] = make_float4(d0 > 0.f ? 1.f / d0 : 0.f,
                        d1 > 0.f ? 1.f / d1 : 0.f,
                        d2 > 0.f ? 1.f / d2 : 0.f, 0.f);
}

// ---- per-node aggregation: pure gather+FMA (r7 version) --------------------
__global__ __launch_bounds__(256) void aggregate_kernel(
    const uint2* __restrict__ wrec, const int* __restrict__ offs,
    const float4* __restrict__ inv4,
    const unsigned short* __restrict__ proj_bf, const float* __restrict__ bias_gat,
    unsigned short* __restrict__ h2bf, int N)
{
  int lane = threadIdx.x & 63;
  int n = blockIdx.x * 4 + (threadIdx.x >> 6);
  if (n >= N) return;
  int lo = offs[n], hi = offs[n + 1];
  float a0 = 0.f, a1 = 0.f, a2 = 0.f;

  int i = lo;
  for (; i + 4 <= hi; i += 4) {
    uint2 r[4];
#pragma unroll
    for (int j = 0; j < 4; ++j) r[j] = wrec[i + j];
    const unsigned short* ps[4];
#pragma unroll
    for (int j = 0; j < 4; ++j)
      ps[j] = &proj_bf[(size_t)(r[j].x & 0xFFFFu) * FDIM];
    float g0[4], g1[4], g2[4];
#pragma unroll
    for (int j = 0; j < 4; ++j) {       // 12 independent gathers in flight
      g0[j] = bf2f(ps[j][lane]);
      g1[j] = bf2f(ps[j][64 + lane]);
      g2[j] = bf2f(ps[j][128 + lane]);
    }
#pragma unroll
    for (int j = 0; j < 4; ++j) {
      a0 += bf2f((unsigned short)(r[j].x >> 16)) * g0[j];
      a1 += bf2f((unsigned short)(r[j].y & 0xFFFFu)) * g1[j];
      a2 += bf2f((unsigned short)(r[j].y >> 16)) * g2[j];
    }
  }
  for (; i < hi; ++i) {
    uint2 r = wrec[i];
    const unsigned short* ps = &proj_bf[(size_t)(r.x & 0xFFFFu) * FDIM];
    a0 += bf2f((unsigned short)(r.x >> 16)) * bf2f(ps[lane]);
    a1 += bf2f((unsigned short)(r.y & 0xFFFFu)) * bf2f(ps[64 + lane]);
    a2 += bf2f((unsigned short)(r.y >> 16)) * bf2f(ps[128 + lane]);
  }

  const float4 inv = inv4[n];
  float r0 = a0 * inv.x + bias_gat[lane];
  float r1 = a1 * inv.y + bias_gat[64 + lane];
  float r2 = a2 * inv.z + bias_gat[128 + lane];
  float h2 = (fmaxf(r0, 0.f) + fmaxf(r1, 0.f) + fmaxf(r2, 0.f)) * (1.f / 3.f);
  h2bf[(size_t)n * 64 + lane] = f2bf(h2);
}

// ---- MLP via MFMA: relu(h2@W1+b1)@W2+b2 + graph atomics (r7 version) -------
__global__ __launch_bounds__(256) void post_mfma_kernel(
    const unsigned short* __restrict__ h2bf,   // [N][64]
    const unsigned short* __restrict__ W1t,    // [128][64]
    const float* __restrict__ b1,
    const unsigned short* __restrict__ W2t,    // [16][128]
    const float* __restrict__ b2, const int* __restrict__ gid,
    float* __restrict__ sums_priv, float* __restrict__ counts_priv, int N)
{
  __shared__ unsigned short z_lds[64 * 128];
  const int wave = threadIdx.x >> 6;
  const int lane = threadIdx.x & 63;
  const int r = lane & 15;
  const int q = lane >> 4;
  const int kg = q * 8;
  const int rw0 = blockIdx.x * 64 + wave * 16;

  int arow = rw0 + r;
  if (arow >= N) arow = N - 1;       // clamp loads; stores guarded

  f32x4 acc1[8];
#pragma unroll
  for (int c = 0; c < 8; ++c) acc1[c] = (f32x4){0.f, 0.f, 0.f, 0.f};

#pragma unroll
  for (int ks = 0; ks < 2; ++ks) {
    bf16x8 a = *reinterpret_cast<const bf16x8*>(&h2bf[(size_t)arow * 64 + kg + ks * 32]);
#pragma unroll
    for (int c = 0; c < 8; ++c) {
      bf16x8 b = *reinterpret_cast<const bf16x8*>(&W1t[(size_t)(c * 16 + r) * 64 + kg + ks * 32]);
      acc1[c] = __builtin_amdgcn_mfma_f32_16x16x32_bf16(a, b, acc1[c], 0, 0, 0);
    }
  }
#pragma unroll
  for (int c = 0; c < 8; ++c) {
    float bb = b1[c * 16 + r];
#pragma unroll
    for (int i = 0; i < 4; ++i) {
      float z = acc1[c][i] + bb;
      z = z > 0.f ? z : 0.f;
      z_lds[(wave * 16 + 4 * q + i) * 128 + c * 16 + r] = f2bf(z);
    }
  }
  __syncthreads();

  f32x4 acc2 = (f32x4){0.f, 0.f, 0.f, 0.f};
#pragma unroll
  for (int ks = 0; ks < 4; ++ks) {
    bf16x8 a = *reinterpret_cast<const bf16x8*>(&z_lds[(wave * 16 + r) * 128 + kg + ks * 32]);
    bf16x8 b = *reinterpret_cast<const bf16x8*>(&W2t[(size_t)r * 128 + kg + ks * 32]);
    acc2 = __builtin_amdgcn_mfma_f32_16x16x32_bf16(a, b, acc2, 0, 0, 0);
  }
  const int part = blockIdx.x & (NPART - 1);
  float bb2 = b2[r];
#pragma unroll
  for (int i = 0; i < 4; ++i) {
    int row = rw0 + 4 * q + i;
    if (row < N) {
      int g = gid[row];
      atomicAdd(&sums_priv[(part * NGRAPH + g) * 16 + r], acc2[i] + bb2);
      if (r == 0) atomicAdd(&counts_priv[part * NGRAPH + g], 1.f);
    }
  }
}

// ---------------- reduce privatized graph sums -> output --------------------
__global__ void finalize_kernel(const float* __restrict__ sums_priv,
                                const float* __restrict__ counts_priv,
                                float* __restrict__ out)
{
  int j = threadIdx.x;            // 0..1023  (g*16 + col)
  int g = j >> 4;
  float s = 0.f, c = 0.f;
  for (int p = 0; p < NPART; ++p) {
    s += sums_priv[p * NGRAPH * 16 + j];
    c += counts_priv[p * NGRAPH + g];
  }
  out[j] = s / fmaxf(c, 1.f);
}

extern "C" void kernel_launch(void* const* d_in, const int* in_sizes, int n_in,
                              void* d_out, int out_size, void* d_ws, size_t ws_size,
                              hipStream_t stream)
{
  const int*   h0  = (const int*)  d_in[0];
  const int*   src = (const int*)  d_in[1];
  const int*   dst = (const int*)  d_in[2];
  const int*   gid = (const int*)  d_in[3];
  const float* emb = (const float*)d_in[4];
  const float* Wfc = (const float*)d_in[5];
  const float* al  = (const float*)d_in[6];
  const float* ar  = (const float*)d_in[7];
  const float* bg  = (const float*)d_in[8];
  const float* W1  = (const float*)d_in[9];
  const float* b1  = (const float*)d_in[10];
  const float* W2  = (const float*)d_in[11];
  const float* b2  = (const float*)d_in[12];
  float* out = (float*)d_out;

  char* ws = (char*)d_ws;
  size_t off = 0;
  auto alloc = [&](size_t bytes) -> void* {
    off = (off + 255) & ~(size_t)255;
    void* p = ws + off;
    off += bytes;
    return p;
  };
  // contiguous zero region: cnt | sums | cnts  (one memset)
  const size_t CNT_B  = (size_t)NNODES * 4;                 // 400000
  const size_t CNT_BP = (CNT_B + 255) & ~(size_t)255;       // 400128
  const size_t SUMS_B = (size_t)NPART * NGRAPH * 16 * 4;    // 262144
  const size_t ZB     = CNT_BP + SUMS_B + (size_t)NPART * NGRAPH * 4;
  char*  zero_base = (char*)alloc(ZB);
  int*   cnt  = (int*)zero_base;
  float* sums = (float*)(zero_base + CNT_BP);
  float* cnts = (float*)(zero_base + CNT_BP + SUMS_B);

  unsigned short* Wt      = (unsigned short*)alloc((size_t)FDIM * HDIM * 2);
  unsigned short* W1t     = (unsigned short*)alloc((size_t)128 * 64 * 2);
  unsigned short* W2t     = (unsigned short*)alloc((size_t)16 * 128 * 2);
  unsigned short* proj_bf = (unsigned short*)alloc((size_t)VOCAB * FDIM * 2);
  unsigned short* h2bf    = (unsigned short*)alloc((size_t)NNODES * 64 * 2);
  unsigned short* recs16  = (unsigned short*)alloc((size_t)NEDGES * 2);
  unsigned short* rank16  = (unsigned short*)alloc((size_t)NEDGES * 2);
  uint2*  wrec   = (uint2*) alloc((size_t)NEDGES * 8);
  float4* elv4   = (float4*)alloc((size_t)VOCAB * 16);
  float4* erv4   = (float4*)alloc((size_t)VOCAB * 16);
  float4* inv4   = (float4*)alloc((size_t)NNODES * 16);
  int*    offs   = (int*)   alloc((size_t)(NNODES + 1) * 4);
  int*    bsum   = (int*)   alloc((size_t)128 * 4);

  hipMemsetAsync(zero_base, 0, ZB, stream);

  const int NB = (NNODES + 1023) / 1024;   // 98

  conv_hist_kernel<<<CONV_BLOCKS + HIST_BLOCKS, 256, 0, stream>>>(
      Wfc, W1, W2, Wt, W1t, W2t, dst, cnt, rank16);
  scan_sum_kernel<<<NB, 256, 0, stream>>>(cnt, bsum, NNODES);
  scan_bsum_kernel<<<1, 64, 0, stream>>>(bsum, NB);
  scan_write_kernel<<<NB, 256, 0, stream>>>(cnt, bsum, offs, NNODES, NEDGES);
  proj_scatter_kernel<<<PROJ_BLOCKS + HIST_BLOCKS, 256, 0, stream>>>(
      emb, Wt, al, ar, proj_bf, elv4, erv4,
      src, dst, h0, rank16, offs, recs16);
  wexp_kernel<<<(NNODES + 255) / 256, 256, 0, stream>>>(recs16, offs, h0, elv4, erv4,
                                                        wrec, inv4, NNODES);
  aggregate_kernel<<<(NNODES + 3) / 4, 256, 0, stream>>>(wrec, offs, inv4, proj_bf,
                                                         bg, h2bf, NNODES);
  post_mfma_kernel<<<(NNODES + 63) / 64, 256, 0, stream>>>(h2bf, W1t, b1, W2t, b2, gid,
                                                           sums, cnts, NNODES);
  finalize_kernel<<<1, 1024, 0, stream>>>(sums, cnts, out);
}